// Round 1
// 605.112 us; speedup vs baseline: 1.3849x; 1.3849x over previous
//
#include <hip/hip_runtime.h>
#include <stdint.h>

typedef unsigned short u16;
typedef short bf16x8 __attribute__((ext_vector_type(8)));
typedef float f32x4 __attribute__((ext_vector_type(4)));

__device__ __forceinline__ float b2f(u16 u){
  unsigned int i = ((unsigned int)u) << 16;
  return __builtin_bit_cast(float, i);
}
__device__ __forceinline__ u16 f2b(float f){
  unsigned int i = __builtin_bit_cast(unsigned int, f);
  i += 0x7FFFu + ((i >> 16) & 1u);   // round-nearest-even
  return (u16)(i >> 16);
}

__device__ __forceinline__ void async16(const void* g, void* l){
  __builtin_amdgcn_global_load_lds((__attribute__((address_space(1))) void*)(void*)g,
                                   (__attribute__((address_space(3))) void*)l, 16, 0, 0);
}

// ---------------- dtype probe: flag=1 if external tensors are fp32 ----------------
__global__ void probe_kernel(const u16* __restrict__ qw, int* __restrict__ flag){
  int cnt = 0;
  for (int i = threadIdx.x; i < 4096; i += 64){
    int e = (qw[i] >> 7) & 0xFF;
    cnt += (e >= 140);
  }
#pragma unroll
  for (int off = 32; off; off >>= 1) cnt += __shfl_down(cnt, off);
  if (threadIdx.x == 0) *flag = (cnt > 64) ? 1 : 0;
}

// ---------------- convert x -> bf16 (8 elems/thread) ----------------
__global__ __launch_bounds__(256) void cvt_kernel(const void* __restrict__ src,
                                                  u16* __restrict__ dst, int n,
                                                  const int* __restrict__ flagp){
  const int i = (blockIdx.x * 256 + threadIdx.x) * 8;
  if (i >= n) return;
  if (*flagp){
    f32x4 a = *(const f32x4*)((const float*)src + i);
    f32x4 b = *(const f32x4*)((const float*)src + i + 4);
    bf16x8 v;
#pragma unroll
    for (int j = 0; j < 4; ++j){ v[j] = (short)f2b(a[j]); v[4+j] = (short)f2b(b[j]); }
    *(bf16x8*)(dst + i) = v;
  } else {
    *(bf16x8*)(dst + i) = *(const bf16x8*)((const u16*)src + i);
  }
}

// ---------------- convert 4 weights -> contiguous bf16 [q;k;v;p] ----------------
__global__ __launch_bounds__(256) void cvtw4_kernel(const void* __restrict__ s0,
                                                    const void* __restrict__ s1,
                                                    const void* __restrict__ s2,
                                                    const void* __restrict__ s3,
                                                    u16* __restrict__ dst,
                                                    const int* __restrict__ flagp){
  const int b = blockIdx.x;                 // 0..1151, 288 blocks per weight
  const int wsel = b / 288;
  const int i = (b - wsel*288) * 2048 + threadIdx.x * 8;   // elem within weight
  const void* src = (wsel == 0) ? s0 : (wsel == 1) ? s1 : (wsel == 2) ? s2 : s3;
  u16* d = dst + (size_t)wsel * 589824 + i;
  if (*flagp){
    f32x4 a = *(const f32x4*)((const float*)src + i);
    f32x4 c = *(const f32x4*)((const float*)src + i + 4);
    bf16x8 v;
#pragma unroll
    for (int j = 0; j < 4; ++j){ v[j] = (short)f2b(a[j]); v[4+j] = (short)f2b(c[j]); }
    *(bf16x8*)d = v;
  } else {
    *(bf16x8*)d = *(const bf16x8*)((const u16*)src + i);
  }
}

// bias -> fp32
__global__ void cvtb_kernel(const void* __restrict__ src, float* __restrict__ dst,
                            int n, const int* __restrict__ flagp){
  int i = blockIdx.x * 256 + threadIdx.x;
  if (i < n) dst[i] = *flagp ? ((const float*)src)[i] : b2f(((const u16*)src)[i]);
}

// ---------------- top-k: rank-by-counting, tie-break lower index ----------------
__global__ __launch_bounds__(576) void topk_kernel(const void* __restrict__ aa,
                                                   int* __restrict__ qrows,
                                                   const int* __restrict__ flagp){
  const int b = blockIdx.x;
  const int isf32 = *flagp;
  __shared__ float vals[576];
  const int i = threadIdx.x;           // 0..575
  const size_t off = (size_t)b*332929 + 1 + i;   // 577*577 = 332929
  vals[i] = isf32 ? ((const float*)aa)[off] : b2f(((const u16*)aa)[off]);
  __syncthreads();
  const float vi = vals[i];
  int rank = 0;
  for (int j = 0; j < 576; ++j){
    float vj = vals[j];
    rank += (int)((vj > vi) || (vj == vi && j < i));
  }
  if (rank < 57) qrows[b*58 + 1 + rank] = b*577 + i + 1;
  if (i == 0)    qrows[b*58] = b*577;
}

// ---------------- fused GEMM ----------------
// mode 0: 1D grid 5376.  bid<5202: (bx=bid%18, by=bid/18) main part over W rows
//         768+nBase (k|v|p), epilogue by n-range: K bf16 | Vt transposed | out fp32+bias.
//         bid>=5202: lq part (bx=t%6, by=t/6), gathered A rows, W rows nBase (q).
// mode 1: 2D grid (6,29): final scatter proj: A=lout, W=pwb, fp32 out + bias, scatter rows.
// Pipeline: 3-deep LDS buffers, counted s_waitcnt vmcnt(4) + raw s_barrier (T3/T4),
// LDS chunk^=(row&3) XOR swizzle applied at global source AND ds_read (T2, rule #21).
__global__ __launch_bounds__(256) void gemm_bt(
    const u16* __restrict__ A, const u16* __restrict__ W,
    u16* __restrict__ Ck, u16* __restrict__ Cvt, float* __restrict__ Cout,
    u16* __restrict__ Clq,
    const int* __restrict__ qrows, const float* __restrict__ bias, int mode)
{
  __shared__ __align__(16) u16 As0[4096], As1[4096], As2[4096];
  __shared__ __align__(16) u16 Bs0[4096], Bs1[4096], Bs2[4096];
  const int tid = threadIdx.x;
  const int w = tid >> 6, l = tid & 63;

  int bx, by; bool lqp = false;
  if (mode == 0){
    const int bid = blockIdx.x;
    if (bid < 5202){ bx = bid % 18; by = bid / 18; }
    else { const int t = bid - 5202; bx = t % 6; by = t / 6; lqp = true; }
  } else { bx = blockIdx.x; by = blockIdx.y; }

  const int mBase = by * 128;
  const int nBase = bx * 128;
  const int Meff  = (mode == 0 && !lqp) ? 36928 : 3712;

  const int r0 = tid >> 2;
  // source chunk pre-swizzled so LDS(r,c) holds global chunk c^(r&3)  [both-sides swizzle]
  const int kc = (((tid & 3) ^ (r0 & 3)) * 8);
  int arow0 = mBase + r0;       if (arow0 > Meff-1) arow0 = Meff-1;
  int arow1 = mBase + 64 + r0;  if (arow1 > Meff-1) arow1 = Meff-1;
  if (mode == 0 && lqp){ arow0 = qrows[arow0]; arow1 = qrows[arow1]; }
  const int wrowBase = (mode == 0 && !lqp) ? (768 + nBase) : nBase;
  const u16* ag0 = A + (size_t)arow0 * 768 + kc;
  const u16* ag1 = A + (size_t)arow1 * 768 + kc;
  const u16* bg0 = W + (size_t)(wrowBase + r0) * 768 + kc;
  const u16* bg1 = W + (size_t)(wrowBase + 64 + r0) * 768 + kc;
  const int toff0 = tid * 8, toff1 = (256 + tid) * 8;

  f32x4 acc[4][4] = {};
  const int wm = (w >> 1) * 64, wn = (w & 1) * 64;
  const int lm = l & 15;
  // swizzled read chunk: want global chunk l>>4 of row with row&3 == l&3
  const int lkx = (((l >> 4) ^ (l & 3)) * 8);

#define STAGE(Ab, Bb, koff) do { \
    async16(ag0 + (koff), &Ab[toff0]); \
    async16(ag1 + (koff), &Ab[toff1]); \
    async16(bg0 + (koff), &Bb[toff0]); \
    async16(bg1 + (koff), &Bb[toff1]); } while(0)

#define COMPUTE(Ab, Bb) { \
    bf16x8 af[4], bfr[4]; \
    _Pragma("unroll") \
    for (int i = 0; i < 4; ++i) af[i]  = *(const bf16x8*)&Ab[(wm + i*16 + lm)*32 + lkx]; \
    _Pragma("unroll") \
    for (int j = 0; j < 4; ++j) bfr[j] = *(const bf16x8*)&Bb[(wn + j*16 + lm)*32 + lkx]; \
    __builtin_amdgcn_s_setprio(1); \
    _Pragma("unroll") \
    for (int i = 0; i < 4; ++i) \
      _Pragma("unroll") \
      for (int j = 0; j < 4; ++j) \
        acc[i][j] = __builtin_amdgcn_mfma_f32_16x16x32_bf16(af[i], bfr[j], acc[i][j], 0, 0, 0); \
    __builtin_amdgcn_s_setprio(0); }

#define VMW4 asm volatile("s_waitcnt vmcnt(4)" ::: "memory")
#define VMW0 asm volatile("s_waitcnt vmcnt(0)" ::: "memory")
#define BAR  __builtin_amdgcn_s_barrier()

  // prologue: tiles 0,1 in flight
  STAGE(As0, Bs0, 0);
  STAGE(As1, Bs1, 32);
  // steady state: at each tile top, 8 loads outstanding -> vmcnt(4) drains the
  // oldest 4 (this tile), keeps next tile's 4 in flight across the barrier.
#pragma unroll
  for (int u = 0; u < 7; ++u){
    const int kb = u * 96;
    VMW4; BAR; STAGE(As2, Bs2, kb + 64);  COMPUTE(As0, Bs0);
    VMW4; BAR; STAGE(As0, Bs0, kb + 96);  COMPUTE(As1, Bs1);
    VMW4; BAR; STAGE(As1, Bs1, kb + 128); COMPUTE(As2, Bs2);
  }
  VMW4; BAR; STAGE(As2, Bs2, 736); COMPUTE(As0, Bs0);   // t=21, stage t=23
  VMW4; BAR;                       COMPUTE(As1, Bs1);   // t=22
  VMW0; BAR;                       COMPUTE(As2, Bs2);   // t=23 (drain)

#undef STAGE
#undef COMPUTE
#undef VMW4
#undef VMW0
#undef BAR

  // epilogue: C layout col=lane&15, row=(lane>>4)*4+reg
  if (mode == 1){
    // final: out[qrows[m]] = lout @ p_w^T + bias   (fp32)
#pragma unroll
    for (int i = 0; i < 4; ++i){
#pragma unroll
      for (int r = 0; r < 4; ++r){
        int m = mBase + wm + i*16 + ((l >> 4) << 2) + r;
        if (m < 3712){
          size_t base = (size_t)qrows[m] * 768;
#pragma unroll
          for (int j = 0; j < 4; ++j){
            int n = nBase + wn + j*16 + lm;
            Cout[base + n] = acc[i][j][r] + bias[n];
          }
        }
      }
    }
    return;
  }
  if (lqp){
    // local_q bf16
#pragma unroll
    for (int i = 0; i < 4; ++i){
#pragma unroll
      for (int r = 0; r < 4; ++r){
        int m = mBase + wm + i*16 + ((l >> 4) << 2) + r;
#pragma unroll
        for (int j = 0; j < 4; ++j){
          int n = nBase + wn + j*16 + lm;
          Clq[(size_t)m*768 + n] = f2b(acc[i][j][r]);
        }
      }
    }
  } else if (nBase < 768){
    // K bf16
#pragma unroll
    for (int i = 0; i < 4; ++i){
#pragma unroll
      for (int r = 0; r < 4; ++r){
        int m = mBase + wm + i*16 + ((l >> 4) << 2) + r;
        if (m < 36928){
#pragma unroll
          for (int j = 0; j < 4; ++j){
            int n = nBase + wn + j*16 + lm;
            Ck[(size_t)m*768 + n] = f2b(acc[i][j][r]);
          }
        }
      }
    }
  } else if (nBase < 1536){
    // Vt transposed per head: [(b*12+h)*64 + d][608]
#pragma unroll
    for (int i = 0; i < 4; ++i){
#pragma unroll
      for (int r = 0; r < 4; ++r){
        int m = mBase + wm + i*16 + ((l >> 4) << 2) + r;
        if (m < 36928){
          int bb = m / 577;
          int nn = m - bb*577;
#pragma unroll
          for (int j = 0; j < 4; ++j){
            int nf = nBase - 768 + wn + j*16 + lm;     // feature = h*64+d
            Cvt[((size_t)(bb*12 + (nf >> 6))*64 + (nf & 63))*608 + nn] = f2b(acc[i][j][r]);
          }
        }
      }
    }
  } else {
    // proj all rows fp32 + bias
#pragma unroll
    for (int i = 0; i < 4; ++i){
#pragma unroll
      for (int r = 0; r < 4; ++r){
        int m = mBase + wm + i*16 + ((l >> 4) << 2) + r;
        if (m < 36928){
          size_t base = (size_t)m * 768;
#pragma unroll
          for (int j = 0; j < 4; ++j){
            int nf = nBase - 1536 + wn + j*16 + lm;
            Cout[base + nf] = acc[i][j][r] + bias[nf];
          }
        }
      }
    }
  }
}

// ---------------- attention: per (m-tile of 16, h, b); exact two-pass softmax ----------------
#define SLD 612   // score LDS row stride (608 data cols + 4 pad)
__global__ __launch_bounds__(256) void attn_kernel(
    const u16* __restrict__ lq, const u16* __restrict__ K,
    const u16* __restrict__ Vt, u16* __restrict__ lout)
{
  const int mt = blockIdx.x, h = blockIdx.y, b = blockIdx.z;
  __shared__ __align__(16) u16 qs[16*64];
  __shared__ __align__(16) float S[16*SLD];
  __shared__ float red[16*17];
  const int tid = threadIdx.x, w = tid >> 6, l = tid & 63;
  const int lm = l & 15, lk = (l >> 4) * 8;

  for (int idx = tid; idx < 1024; idx += 256){
    int r = idx >> 6, c = idx & 63;
    int gm = mt*16 + r;
    qs[idx] = (gm < 58) ? lq[((size_t)b*58 + gm)*768 + h*64 + c] : (u16)0;
  }
  __syncthreads();
  bf16x8 aq0 = *(const bf16x8*)&qs[lm*64 + lk];
  bf16x8 aq1 = *(const bf16x8*)&qs[lm*64 + 32 + lk];

  // scores: S[m][n] = (Q·K^T)*0.125, n padded to 608
  const u16* Kb = K + (size_t)b*577*768 + h*64;
  for (int t = w; t < 38; t += 4){
    int n0 = t*16;
    int n = n0 + lm; if (n > 576) n = 576;
    const u16* kp = Kb + (size_t)n*768;
    bf16x8 b0 = *(const bf16x8*)&kp[lk];
    bf16x8 b1 = *(const bf16x8*)&kp[32 + lk];
    f32x4 c = {};
    c = __builtin_amdgcn_mfma_f32_16x16x32_bf16(aq0, b0, c, 0, 0, 0);
    c = __builtin_amdgcn_mfma_f32_16x16x32_bf16(aq1, b1, c, 0, 0, 0);
#pragma unroll
    for (int r = 0; r < 4; ++r)
      S[(((l >> 4) << 2) + r)*SLD + n0 + lm] = c[r] * 0.125f;
  }
  __syncthreads();

  // softmax over n<577, 16 threads per row
  const int row = tid >> 4, g = tid & 15;
  float mx = -1e30f;
  for (int n = g; n < 577; n += 16) mx = fmaxf(mx, S[row*SLD + n]);
  red[row*17 + g] = mx;
  __syncthreads();
  float m2 = red[row*17];
#pragma unroll
  for (int i = 1; i < 16; ++i) m2 = fmaxf(m2, red[row*17 + i]);
  float sum = 0.f;
  for (int n = g; n < 577; n += 16){
    float e = __expf(S[row*SLD + n] - m2);
    S[row*SLD + n] = e;
    sum += e;
  }
  __syncthreads();
  red[row*17 + g] = sum;
  __syncthreads();
  float s2 = 0.f;
#pragma unroll
  for (int i = 0; i < 16; ++i) s2 += red[row*17 + i];
  float inv = 1.f / s2;
  for (int n = g; n < 577; n += 16) S[row*SLD + n] *= inv;
  for (int n = 577 + g; n < 608; n += 16) S[row*SLD + n] = 0.f;
  __syncthreads();

  // O = P · V via Vt[b][h][d][n]; wave w owns d-tile w
  const u16* Vb = Vt + ((size_t)(b*12 + h) * 64) * 608;
  f32x4 oc = {};
  for (int ks = 0; ks < 19; ++ks){
    int kb = ks*32 + lk;
    f32x4 p0 = *(const f32x4*)&S[lm*SLD + kb];
    f32x4 p1 = *(const f32x4*)&S[lm*SLD + kb + 4];
    bf16x8 af;
#pragma unroll
    for (int j = 0; j < 4; ++j){ af[j] = (short)f2b(p0[j]); af[4+j] = (short)f2b(p1[j]); }
    bf16x8 bv = *(const bf16x8*)&Vb[(size_t)(w*16 + lm)*608 + kb];
    oc = __builtin_amdgcn_mfma_f32_16x16x32_bf16(af, bv, oc, 0, 0, 0);
  }
#pragma unroll
  for (int r = 0; r < 4; ++r){
    int ml = mt*16 + ((l >> 4) << 2) + r;
    if (ml < 58)
      lout[((size_t)b*58 + ml)*768 + h*64 + w*16 + lm] = f2b(oc[r]);
  }
}

// ---------------- launch ----------------
extern "C" void kernel_launch(void* const* d_in, const int* in_sizes, int n_in,
                              void* d_out, int out_size, void* d_ws, size_t ws_size,
                              hipStream_t stream)
{
  const void* x    = d_in[0];
  const void* aacc = d_in[1];
  const void* q_w  = d_in[2];
  const void* k_w  = d_in[3];
  const void* v_w  = d_in[4];
  const void* p_w  = d_in[5];
  const void* p_b  = d_in[6];

  const int M  = 36928;   // 64*577
  const int Ms = 3712;    // 64*58
  const int XE = M * 768;       // 28,360,704
  const int WE = 768 * 768;     // 589,824

  u16* Kbuf = (u16*)d_ws;                              // 36928*768
  u16* Vt   = Kbuf + (size_t)M * 768;                  // 768*64*608 (b*12+h, d, n)
  u16* lq   = Vt + (size_t)768 * 64 * 608;             // 3712*768
  u16* lout = lq + (size_t)Ms * 768;                   // 3712*768
  u16* xb   = lout + (size_t)Ms * 768;                 // 36928*768 bf16 x
  u16* qwb  = xb + (size_t)XE;                         // 4 weights bf16 [q;k;v;p]
  u16* pwb  = qwb + (size_t)3 * WE;
  float* biasf = (float*)(qwb + (size_t)4 * WE);       // 768 fp32
  int* qrows = (int*)(biasf + 768);                    // 3712 ints
  int* flagp = qrows + 3712;

  probe_kernel<<<1, 64, 0, stream>>>((const u16*)q_w, flagp);
  cvt_kernel<<<XE/8/256, 256, 0, stream>>>(x, xb, XE, flagp);
  cvtw4_kernel<<<1152, 256, 0, stream>>>(q_w, k_w, v_w, p_w, qwb, flagp);
  cvtb_kernel<<<3, 256, 0, stream>>>(p_b, biasf, 768, flagp);
  topk_kernel<<<64, 576, 0, stream>>>(aacc, qrows, flagp);

  // fused: K | Vt | proj-out (18 n-tiles x 289 m-tiles) + gathered lq (6 x 29)
  gemm_bt<<<5376, 256, 0, stream>>>(xb, qwb, Kbuf, Vt, (float*)d_out, lq,
                                    qrows, biasf, 0);
  // attention -> local_out
  attn_kernel<<<dim3(4, 12, 64), 256, 0, stream>>>(lq, Kbuf, Vt, lout);
  // overwrite selected rows: out[qrows] = local_out @ proj_w^T + b
  gemm_bt<<<dim3(6, 29), 256, 0, stream>>>(lout, pwb, nullptr, nullptr,
                                           (float*)d_out, nullptr, qrows, biasf, 1);
}

// Round 2
// 578.164 us; speedup vs baseline: 1.4495x; 1.0466x over previous
//
#include <hip/hip_runtime.h>
#include <stdint.h>

typedef unsigned short u16;
typedef short bf16x8 __attribute__((ext_vector_type(8)));
typedef float f32x4 __attribute__((ext_vector_type(4)));

__device__ __forceinline__ float b2f(u16 u){
  unsigned int i = ((unsigned int)u) << 16;
  return __builtin_bit_cast(float, i);
}
__device__ __forceinline__ u16 f2b(float f){
  unsigned int i = __builtin_bit_cast(unsigned int, f);
  i += 0x7FFFu + ((i >> 16) & 1u);   // round-nearest-even
  return (u16)(i >> 16);
}

__device__ __forceinline__ void async16(const void* g, void* l){
  __builtin_amdgcn_global_load_lds((__attribute__((address_space(1))) void*)(void*)g,
                                   (__attribute__((address_space(3))) void*)l, 16, 0, 0);
}

// ---------------- dtype probe: flag=1 if external tensors are fp32 ----------------
__global__ void probe_kernel(const u16* __restrict__ qw, int* __restrict__ flag){
  int cnt = 0;
  for (int i = threadIdx.x; i < 4096; i += 64){
    int e = (qw[i] >> 7) & 0xFF;
    cnt += (e >= 140);
  }
#pragma unroll
  for (int off = 32; off; off >>= 1) cnt += __shfl_down(cnt, off);
  if (threadIdx.x == 0) *flag = (cnt > 64) ? 1 : 0;
}

// ---------------- convert x -> bf16 (8 elems/thread) ----------------
__global__ __launch_bounds__(256) void cvt_kernel(const void* __restrict__ src,
                                                  u16* __restrict__ dst, int n,
                                                  const int* __restrict__ flagp){
  const int i = (blockIdx.x * 256 + threadIdx.x) * 8;
  if (i >= n) return;
  if (*flagp){
    f32x4 a = *(const f32x4*)((const float*)src + i);
    f32x4 b = *(const f32x4*)((const float*)src + i + 4);
    bf16x8 v;
#pragma unroll
    for (int j = 0; j < 4; ++j){ v[j] = (short)f2b(a[j]); v[4+j] = (short)f2b(b[j]); }
    *(bf16x8*)(dst + i) = v;
  } else {
    *(bf16x8*)(dst + i) = *(const bf16x8*)((const u16*)src + i);
  }
}

// ---------------- convert 4 weights -> contiguous bf16 [q;k;v;p] ----------------
__global__ __launch_bounds__(256) void cvtw4_kernel(const void* __restrict__ s0,
                                                    const void* __restrict__ s1,
                                                    const void* __restrict__ s2,
                                                    const void* __restrict__ s3,
                                                    u16* __restrict__ dst,
                                                    const int* __restrict__ flagp){
  const int b = blockIdx.x;                 // 0..1151, 288 blocks per weight
  const int wsel = b / 288;
  const int i = (b - wsel*288) * 2048 + threadIdx.x * 8;   // elem within weight
  const void* src = (wsel == 0) ? s0 : (wsel == 1) ? s1 : (wsel == 2) ? s2 : s3;
  u16* d = dst + (size_t)wsel * 589824 + i;
  if (*flagp){
    f32x4 a = *(const f32x4*)((const float*)src + i);
    f32x4 c = *(const f32x4*)((const float*)src + i + 4);
    bf16x8 v;
#pragma unroll
    for (int j = 0; j < 4; ++j){ v[j] = (short)f2b(a[j]); v[4+j] = (short)f2b(c[j]); }
    *(bf16x8*)d = v;
  } else {
    *(bf16x8*)d = *(const bf16x8*)((const u16*)src + i);
  }
}

// bias -> fp32
__global__ void cvtb_kernel(const void* __restrict__ src, float* __restrict__ dst,
                            int n, const int* __restrict__ flagp){
  int i = blockIdx.x * 256 + threadIdx.x;
  if (i < n) dst[i] = *flagp ? ((const float*)src)[i] : b2f(((const u16*)src)[i]);
}

// ---------------- top-k: rank-by-counting, tie-break lower index ----------------
__global__ __launch_bounds__(576) void topk_kernel(const void* __restrict__ aa,
                                                   int* __restrict__ qrows,
                                                   const int* __restrict__ flagp){
  const int b = blockIdx.x;
  const int isf32 = *flagp;
  __shared__ float vals[576];
  const int i = threadIdx.x;           // 0..575
  const size_t off = (size_t)b*332929 + 1 + i;   // 577*577 = 332929
  vals[i] = isf32 ? ((const float*)aa)[off] : b2f(((const u16*)aa)[off]);
  __syncthreads();
  const float vi = vals[i];
  int rank = 0;
  for (int j = 0; j < 576; ++j){
    float vj = vals[j];
    rank += (int)((vj > vi) || (vj == vi && j < i));
  }
  if (rank < 57) qrows[b*58 + 1 + rank] = b*577 + i + 1;
  if (i == 0)    qrows[b*58] = b*577;
}

// ---------------- fused GEMM ----------------
// mode 0: 1D grid 5376, XCD-chunked: wg=(bid&7)*672+(bid>>3) so each XCD owns a
//         contiguous m-tile range (A-panel fetched once per L2 instead of 8x).
//         wg<5202: (bx=wg%18, by=wg/18) main part over W rows 768+nBase (k|v|p),
//         epilogue by n-range: K bf16 | Vt transposed | out fp32+bias.
//         wg>=5202: lq part (bx=t%6, by=t/6), gathered A rows, W rows nBase (q).
// mode 1: 2D grid (6,29): final scatter proj: A=lout, W=pwb, fp32 out + bias.
// Pipeline: 3-deep LDS buffers, counted s_waitcnt vmcnt(4) + raw s_barrier (T3/T4).
// LDS swizzle: chunk ^= (row>>1)&3 — row stride is 64B=16 banks so bank=(row&1,chunk);
// this makes (row&1,chunk) bijective over 8 rows -> even 2/bank spread (rule #21:
// applied at global source AND ds_read).
__global__ __launch_bounds__(256) void gemm_bt(
    const u16* __restrict__ A, const u16* __restrict__ W,
    u16* __restrict__ Ck, u16* __restrict__ Cvt, float* __restrict__ Cout,
    u16* __restrict__ Clq,
    const int* __restrict__ qrows, const float* __restrict__ bias, int mode)
{
  __shared__ __align__(16) u16 As0[4096], As1[4096], As2[4096];
  __shared__ __align__(16) u16 Bs0[4096], Bs1[4096], Bs2[4096];
  const int tid = threadIdx.x;
  const int w = tid >> 6, l = tid & 63;

  int bx, by; bool lqp = false;
  if (mode == 0){
    const int bid = blockIdx.x;
    const int wg = (bid & 7) * 672 + (bid >> 3);   // 5376 = 8*672 exact (bijective)
    if (wg < 5202){ bx = wg % 18; by = wg / 18; }
    else { const int t = wg - 5202; bx = t % 6; by = t / 6; lqp = true; }
  } else { bx = blockIdx.x; by = blockIdx.y; }

  const int mBase = by * 128;
  const int nBase = bx * 128;
  const int Meff  = (mode == 0 && !lqp) ? 36928 : 3712;

  const int r0 = tid >> 2;
  // source chunk pre-swizzled so LDS(r,c) holds global chunk c^((r>>1)&3)
  const int kc = (((tid & 3) ^ ((r0 >> 1) & 3)) * 8);
  int arow0 = mBase + r0;       if (arow0 > Meff-1) arow0 = Meff-1;
  int arow1 = mBase + 64 + r0;  if (arow1 > Meff-1) arow1 = Meff-1;
  if (mode == 0 && lqp){ arow0 = qrows[arow0]; arow1 = qrows[arow1]; }
  const int wrowBase = (mode == 0 && !lqp) ? (768 + nBase) : nBase;
  const u16* ag0 = A + (size_t)arow0 * 768 + kc;
  const u16* ag1 = A + (size_t)arow1 * 768 + kc;
  const u16* bg0 = W + (size_t)(wrowBase + r0) * 768 + kc;
  const u16* bg1 = W + (size_t)(wrowBase + 64 + r0) * 768 + kc;
  const int toff0 = tid * 8, toff1 = (256 + tid) * 8;

  f32x4 acc[4][4] = {};
  const int wm = (w >> 1) * 64, wn = (w & 1) * 64;
  const int lm = l & 15;
  // swizzled read chunk: global chunk l>>4 of row with (row>>1)&3 == (l>>1)&3
  const int lkx = (((l >> 4) ^ ((l >> 1) & 3)) * 8);

#define STAGE(Ab, Bb, koff) do { \
    async16(ag0 + (koff), &Ab[toff0]); \
    async16(ag1 + (koff), &Ab[toff1]); \
    async16(bg0 + (koff), &Bb[toff0]); \
    async16(bg1 + (koff), &Bb[toff1]); } while(0)

#define COMPUTE(Ab, Bb) { \
    bf16x8 af[4], bfr[4]; \
    _Pragma("unroll") \
    for (int i = 0; i < 4; ++i) af[i]  = *(const bf16x8*)&Ab[(wm + i*16 + lm)*32 + lkx]; \
    _Pragma("unroll") \
    for (int j = 0; j < 4; ++j) bfr[j] = *(const bf16x8*)&Bb[(wn + j*16 + lm)*32 + lkx]; \
    __builtin_amdgcn_s_setprio(1); \
    _Pragma("unroll") \
    for (int i = 0; i < 4; ++i) \
      _Pragma("unroll") \
      for (int j = 0; j < 4; ++j) \
        acc[i][j] = __builtin_amdgcn_mfma_f32_16x16x32_bf16(af[i], bfr[j], acc[i][j], 0, 0, 0); \
    __builtin_amdgcn_s_setprio(0); }

#define VMW4 asm volatile("s_waitcnt vmcnt(4)" ::: "memory")
#define VMW0 asm volatile("s_waitcnt vmcnt(0)" ::: "memory")
#define BAR  __builtin_amdgcn_s_barrier()

  // prologue: tiles 0,1 in flight
  STAGE(As0, Bs0, 0);
  STAGE(As1, Bs1, 32);
  // steady state: at each tile top, 8 loads outstanding -> vmcnt(4) drains the
  // oldest 4 (this tile), keeps next tile's 4 in flight across the barrier.
#pragma unroll
  for (int u = 0; u < 7; ++u){
    const int kb = u * 96;
    VMW4; BAR; STAGE(As2, Bs2, kb + 64);  COMPUTE(As0, Bs0);
    VMW4; BAR; STAGE(As0, Bs0, kb + 96);  COMPUTE(As1, Bs1);
    VMW4; BAR; STAGE(As1, Bs1, kb + 128); COMPUTE(As2, Bs2);
  }
  VMW4; BAR; STAGE(As2, Bs2, 736); COMPUTE(As0, Bs0);   // t=21, stage t=23
  VMW4; BAR;                       COMPUTE(As1, Bs1);   // t=22
  VMW0; BAR;                       COMPUTE(As2, Bs2);   // t=23 (drain)

#undef STAGE
#undef COMPUTE
#undef VMW4
#undef VMW0
#undef BAR

  // epilogue: C layout col=lane&15, row=(lane>>4)*4+reg
  if (mode == 1){
    // final: out[qrows[m]] = lout @ p_w^T + bias   (fp32)
#pragma unroll
    for (int i = 0; i < 4; ++i){
#pragma unroll
      for (int r = 0; r < 4; ++r){
        int m = mBase + wm + i*16 + ((l >> 4) << 2) + r;
        if (m < 3712){
          size_t base = (size_t)qrows[m] * 768;
#pragma unroll
          for (int j = 0; j < 4; ++j){
            int n = nBase + wn + j*16 + lm;
            Cout[base + n] = acc[i][j][r] + bias[n];
          }
        }
      }
    }
    return;
  }
  if (lqp){
    // local_q bf16
#pragma unroll
    for (int i = 0; i < 4; ++i){
#pragma unroll
      for (int r = 0; r < 4; ++r){
        int m = mBase + wm + i*16 + ((l >> 4) << 2) + r;
#pragma unroll
        for (int j = 0; j < 4; ++j){
          int n = nBase + wn + j*16 + lm;
          Clq[(size_t)m*768 + n] = f2b(acc[i][j][r]);
        }
      }
    }
  } else if (nBase < 768){
    // K bf16
#pragma unroll
    for (int i = 0; i < 4; ++i){
#pragma unroll
      for (int r = 0; r < 4; ++r){
        int m = mBase + wm + i*16 + ((l >> 4) << 2) + r;
        if (m < 36928){
#pragma unroll
          for (int j = 0; j < 4; ++j){
            int n = nBase + wn + j*16 + lm;
            Ck[(size_t)m*768 + n] = f2b(acc[i][j][r]);
          }
        }
      }
    }
  } else if (nBase < 1536){
    // Vt transposed per head: [(b*12+h)*64 + d][608]
#pragma unroll
    for (int i = 0; i < 4; ++i){
#pragma unroll
      for (int r = 0; r < 4; ++r){
        int m = mBase + wm + i*16 + ((l >> 4) << 2) + r;
        if (m < 36928){
          int bb = m / 577;
          int nn = m - bb*577;
#pragma unroll
          for (int j = 0; j < 4; ++j){
            int nf = nBase - 768 + wn + j*16 + lm;     // feature = h*64+d
            Cvt[((size_t)(bb*12 + (nf >> 6))*64 + (nf & 63))*608 + nn] = f2b(acc[i][j][r]);
          }
        }
      }
    }
  } else {
    // proj all rows fp32 + bias
#pragma unroll
    for (int i = 0; i < 4; ++i){
#pragma unroll
      for (int r = 0; r < 4; ++r){
        int m = mBase + wm + i*16 + ((l >> 4) << 2) + r;
        if (m < 36928){
          size_t base = (size_t)m * 768;
#pragma unroll
          for (int j = 0; j < 4; ++j){
            int nf = nBase - 1536 + wn + j*16 + lm;
            Cout[base + nf] = acc[i][j][r] + bias[nf];
          }
        }
      }
    }
  }
}

// ---------------- attention: 1D grid 3072, XCD-chunked so the 4 m-tiles of a
// (h,b) pair share one XCD's L2 (K/Vt slice fetched once, reused 4x).
// S shrunk to stride-580 fp32 (no 608 zero-pad; n=576 PV tail is a scalar FMA)
// and red aliased onto qs -> LDS 39.2KB -> 4 blocks/CU (was 3).
#define SLD 580   // score LDS row stride in floats (577 data + 3 pad)
__global__ __launch_bounds__(256) void attn_kernel(
    const u16* __restrict__ lq, const u16* __restrict__ K,
    const u16* __restrict__ Vt, u16* __restrict__ lout)
{
  const int bid = blockIdx.x;
  const int wg = (bid & 7) * 384 + (bid >> 3);   // 3072 = 8*384 exact
  const int mt = wg & 3;
  const int hb = wg >> 2;
  const int h = hb % 12, b = hb / 12;

  __shared__ __align__(16) u16 qs[16*64];        // reused as red after scores
  __shared__ __align__(16) float S[16*SLD];
  float* red = (float*)qs;                       // 16*17*4 = 1088B <= 2048B
  const int tid = threadIdx.x, w = tid >> 6, l = tid & 63;
  const int lm = l & 15, lk = (l >> 4) * 8;

  for (int idx = tid; idx < 1024; idx += 256){
    int r = idx >> 6, c = idx & 63;
    int gm = mt*16 + r;
    qs[idx] = (gm < 58) ? lq[((size_t)b*58 + gm)*768 + h*64 + c] : (u16)0;
  }
  __syncthreads();
  bf16x8 aq0 = *(const bf16x8*)&qs[lm*64 + lk];
  bf16x8 aq1 = *(const bf16x8*)&qs[lm*64 + 32 + lk];

  // scores: S[m][n] = (Q·K^T)*0.125 for n<577
  const u16* Kb = K + (size_t)b*577*768 + h*64;
  for (int t = w; t < 37; t += 4){
    int n0 = t*16;
    int n = n0 + lm; if (n > 576) n = 576;
    const u16* kp = Kb + (size_t)n*768;
    bf16x8 b0 = *(const bf16x8*)&kp[lk];
    bf16x8 b1 = *(const bf16x8*)&kp[32 + lk];
    f32x4 c = {};
    c = __builtin_amdgcn_mfma_f32_16x16x32_bf16(aq0, b0, c, 0, 0, 0);
    c = __builtin_amdgcn_mfma_f32_16x16x32_bf16(aq1, b1, c, 0, 0, 0);
    if (n0 + lm < 577){
#pragma unroll
      for (int r = 0; r < 4; ++r)
        S[(((l >> 4) << 2) + r)*SLD + n0 + lm] = c[r] * 0.125f;
    }
  }
  __syncthreads();

  // softmax over n<577, 16 threads per row
  const int row = tid >> 4, g = tid & 15;
  float mx = -1e30f;
  for (int n = g; n < 577; n += 16) mx = fmaxf(mx, S[row*SLD + n]);
  red[row*17 + g] = mx;
  __syncthreads();
  float m2 = red[row*17];
#pragma unroll
  for (int i = 1; i < 16; ++i) m2 = fmaxf(m2, red[row*17 + i]);
  float sum = 0.f;
  for (int n = g; n < 577; n += 16){
    float e = __expf(S[row*SLD + n] - m2);
    S[row*SLD + n] = e;
    sum += e;
  }
  __syncthreads();
  red[row*17 + g] = sum;
  __syncthreads();
  float s2 = 0.f;
#pragma unroll
  for (int i = 0; i < 16; ++i) s2 += red[row*17 + i];
  float inv = 1.f / s2;
  for (int n = g; n < 577; n += 16) S[row*SLD + n] *= inv;
  __syncthreads();

  // O = P · V via Vt[b][h][d][n]; wave w owns d-tile w.  n=0..575 via MFMA.
  const u16* Vb = Vt + ((size_t)(b*12 + h) * 64) * 608;
  f32x4 oc = {};
  for (int ks = 0; ks < 18; ++ks){
    int kb = ks*32 + lk;
    f32x4 p0 = *(const f32x4*)&S[lm*SLD + kb];
    f32x4 p1 = *(const f32x4*)&S[lm*SLD + kb + 4];
    bf16x8 af;
#pragma unroll
    for (int j = 0; j < 4; ++j){ af[j] = (short)f2b(p0[j]); af[4+j] = (short)f2b(p1[j]); }
    bf16x8 bv = *(const bf16x8*)&Vb[(size_t)(w*16 + lm)*608 + kb];
    oc = __builtin_amdgcn_mfma_f32_16x16x32_bf16(af, bv, oc, 0, 0, 0);
  }
  // tail n=576 (fp32 scalar FMA; Vt cols 577+ are never touched)
  {
    float vt576 = b2f(Vb[(size_t)(w*16 + lm)*608 + 576]);
#pragma unroll
    for (int r = 0; r < 4; ++r)
      oc[r] += S[(((l >> 4) << 2) + r)*SLD + 576] * vt576;
  }
#pragma unroll
  for (int r = 0; r < 4; ++r){
    int ml = mt*16 + ((l >> 4) << 2) + r;
    if (ml < 58)
      lout[((size_t)b*58 + ml)*768 + h*64 + w*16 + lm] = f2b(oc[r]);
  }
}

// ---------------- launch ----------------
extern "C" void kernel_launch(void* const* d_in, const int* in_sizes, int n_in,
                              void* d_out, int out_size, void* d_ws, size_t ws_size,
                              hipStream_t stream)
{
  const void* x    = d_in[0];
  const void* aacc = d_in[1];
  const void* q_w  = d_in[2];
  const void* k_w  = d_in[3];
  const void* v_w  = d_in[4];
  const void* p_w  = d_in[5];
  const void* p_b  = d_in[6];

  const int M  = 36928;   // 64*577
  const int Ms = 3712;    // 64*58
  const int XE = M * 768;       // 28,360,704
  const int WE = 768 * 768;     // 589,824

  u16* Kbuf = (u16*)d_ws;                              // 36928*768
  u16* Vt   = Kbuf + (size_t)M * 768;                  // 768*64*608 (b*12+h, d, n)
  u16* lq   = Vt + (size_t)768 * 64 * 608;             // 3712*768
  u16* lout = lq + (size_t)Ms * 768;                   // 3712*768
  u16* xb   = lout + (size_t)Ms * 768;                 // 36928*768 bf16 x
  u16* qwb  = xb + (size_t)XE;                         // 4 weights bf16 [q;k;v;p]
  u16* pwb  = qwb + (size_t)3 * WE;
  float* biasf = (float*)(qwb + (size_t)4 * WE);       // 768 fp32
  int* qrows = (int*)(biasf + 768);                    // 3712 ints
  int* flagp = qrows + 3712;

  probe_kernel<<<1, 64, 0, stream>>>((const u16*)q_w, flagp);
  cvt_kernel<<<XE/8/256, 256, 0, stream>>>(x, xb, XE, flagp);
  cvtw4_kernel<<<1152, 256, 0, stream>>>(q_w, k_w, v_w, p_w, qwb, flagp);
  cvtb_kernel<<<3, 256, 0, stream>>>(p_b, biasf, 768, flagp);
  topk_kernel<<<64, 576, 0, stream>>>(aacc, qrows, flagp);

  // fused: K | Vt | proj-out (18 n-tiles x 289 m-tiles) + gathered lq (6 x 29)
  gemm_bt<<<5376, 256, 0, stream>>>(xb, qwb, Kbuf, Vt, (float*)d_out, lq,
                                    qrows, biasf, 0);
  // attention -> local_out
  attn_kernel<<<3072, 256, 0, stream>>>(lq, Kbuf, Vt, lout);
  // overwrite selected rows: out[qrows] = local_out @ proj_w^T + b
  gemm_bt<<<dim3(6, 29), 256, 0, stream>>>(lout, pwb, nullptr, nullptr,
                                           (float*)d_out, nullptr, qrows, biasf, 1);
}

// Round 3
// 576.001 us; speedup vs baseline: 1.4549x; 1.0038x over previous
//
#include <hip/hip_runtime.h>
#include <stdint.h>

typedef unsigned short u16;
typedef short bf16x8 __attribute__((ext_vector_type(8)));
typedef float f32x4 __attribute__((ext_vector_type(4)));

__device__ __forceinline__ float b2f(u16 u){
  unsigned int i = ((unsigned int)u) << 16;
  return __builtin_bit_cast(float, i);
}
__device__ __forceinline__ u16 f2b(float f){
  unsigned int i = __builtin_bit_cast(unsigned int, f);
  i += 0x7FFFu + ((i >> 16) & 1u);   // round-nearest-even
  return (u16)(i >> 16);
}

__device__ __forceinline__ void async16(const void* g, void* l){
  __builtin_amdgcn_global_load_lds((__attribute__((address_space(1))) void*)(void*)g,
                                   (__attribute__((address_space(3))) void*)l, 16, 0, 0);
}

// ---------------- dtype probe: flag=1 if external tensors are fp32 ----------------
__global__ void probe_kernel(const u16* __restrict__ qw, int* __restrict__ flag){
  int cnt = 0;
  for (int i = threadIdx.x; i < 4096; i += 64){
    int e = (qw[i] >> 7) & 0xFF;
    cnt += (e >= 140);
  }
#pragma unroll
  for (int off = 32; off; off >>= 1) cnt += __shfl_down(cnt, off);
  if (threadIdx.x == 0) *flag = (cnt > 64) ? 1 : 0;
}

// ---------------- convert x -> bf16 (8 elems/thread) ----------------
__global__ __launch_bounds__(256) void cvt_kernel(const void* __restrict__ src,
                                                  u16* __restrict__ dst, int n,
                                                  const int* __restrict__ flagp){
  const int i = (blockIdx.x * 256 + threadIdx.x) * 8;
  if (i >= n) return;
  if (*flagp){
    f32x4 a = *(const f32x4*)((const float*)src + i);
    f32x4 b = *(const f32x4*)((const float*)src + i + 4);
    bf16x8 v;
#pragma unroll
    for (int j = 0; j < 4; ++j){ v[j] = (short)f2b(a[j]); v[4+j] = (short)f2b(b[j]); }
    *(bf16x8*)(dst + i) = v;
  } else {
    *(bf16x8*)(dst + i) = *(const bf16x8*)((const u16*)src + i);
  }
}

// ---------------- convert 4 weights -> contiguous bf16 [q;k;v;p] ----------------
__global__ __launch_bounds__(256) void cvtw4_kernel(const void* __restrict__ s0,
                                                    const void* __restrict__ s1,
                                                    const void* __restrict__ s2,
                                                    const void* __restrict__ s3,
                                                    u16* __restrict__ dst,
                                                    const int* __restrict__ flagp){
  const int b = blockIdx.x;                 // 0..1151, 288 blocks per weight
  const int wsel = b / 288;
  const int i = (b - wsel*288) * 2048 + threadIdx.x * 8;   // elem within weight
  const void* src = (wsel == 0) ? s0 : (wsel == 1) ? s1 : (wsel == 2) ? s2 : s3;
  u16* d = dst + (size_t)wsel * 589824 + i;
  if (*flagp){
    f32x4 a = *(const f32x4*)((const float*)src + i);
    f32x4 c = *(const f32x4*)((const float*)src + i + 4);
    bf16x8 v;
#pragma unroll
    for (int j = 0; j < 4; ++j){ v[j] = (short)f2b(a[j]); v[4+j] = (short)f2b(c[j]); }
    *(bf16x8*)d = v;
  } else {
    *(bf16x8*)d = *(const bf16x8*)((const u16*)src + i);
  }
}

// bias -> fp32
__global__ void cvtb_kernel(const void* __restrict__ src, float* __restrict__ dst,
                            int n, const int* __restrict__ flagp){
  int i = blockIdx.x * 256 + threadIdx.x;
  if (i < n) dst[i] = *flagp ? ((const float*)src)[i] : b2f(((const u16*)src)[i]);
}

// ---------------- top-k: rank-by-counting, tie-break lower index ----------------
__global__ __launch_bounds__(576) void topk_kernel(const void* __restrict__ aa,
                                                   int* __restrict__ qrows,
                                                   const int* __restrict__ flagp){
  const int b = blockIdx.x;
  const int isf32 = *flagp;
  __shared__ float vals[576];
  const int i = threadIdx.x;           // 0..575
  const size_t off = (size_t)b*332929 + 1 + i;   // 577*577 = 332929
  vals[i] = isf32 ? ((const float*)aa)[off] : b2f(((const u16*)aa)[off]);
  __syncthreads();
  const float vi = vals[i];
  int rank = 0;
  for (int j = 0; j < 576; ++j){
    float vj = vals[j];
    rank += (int)((vj > vi) || (vj == vi && j < i));
  }
  if (rank < 57) qrows[b*58 + 1 + rank] = b*577 + i + 1;
  if (i == 0)    qrows[b*58] = b*577;
}

// ---------------- fused GEMM ----------------
// mode 0: 1D grid 5376, XCD-chunked: wg=(bid&7)*672+(bid>>3).
//         wg<5202: (bx=wg%18, by=wg/18) main part over W rows 768+nBase (k|v|p),
//         epilogue by n-range: K bf16 | Vt transposed | out fp32+bias.
//         wg>=5202: lq part, gathered A rows, W rows nBase (q).
// mode 1: 2D grid (6,29): final scatter proj: A=lout, W=pwb, fp32 out + bias.
// Pipeline: 2-deep LDS dbuf (32KB -> 5 LDS-blocks/CU), counted s_waitcnt vmcnt(4)
// keeps next tile's 4 loads in flight across the barrier (T3/T4).
// __launch_bounds__(256,4): cap regs at 128 (acc=64 AGPR) -> 4 blocks/CU.
// LDS swizzle: chunk ^= (row>>1)&3, applied at global source AND ds_read (rule #21).
__global__ __launch_bounds__(256, 4) void gemm_bt(
    const u16* __restrict__ A, const u16* __restrict__ W,
    u16* __restrict__ Ck, u16* __restrict__ Cvt, float* __restrict__ Cout,
    u16* __restrict__ Clq,
    const int* __restrict__ qrows, const float* __restrict__ bias, int mode)
{
  __shared__ __align__(16) u16 As0[4096], As1[4096];
  __shared__ __align__(16) u16 Bs0[4096], Bs1[4096];
  const int tid = threadIdx.x;
  const int w = tid >> 6, l = tid & 63;

  int bx, by; bool lqp = false;
  if (mode == 0){
    const int bid = blockIdx.x;
    const int wg = (bid & 7) * 672 + (bid >> 3);   // 5376 = 8*672 exact (bijective)
    if (wg < 5202){ bx = wg % 18; by = wg / 18; }
    else { const int t = wg - 5202; bx = t % 6; by = t / 6; lqp = true; }
  } else { bx = blockIdx.x; by = blockIdx.y; }

  const int mBase = by * 128;
  const int nBase = bx * 128;
  const int Meff  = (mode == 0 && !lqp) ? 36928 : 3712;

  const int r0 = tid >> 2;
  // source chunk pre-swizzled so LDS(r,c) holds global chunk c^((r>>1)&3)
  const int kc = (((tid & 3) ^ ((r0 >> 1) & 3)) * 8);
  int arow0 = mBase + r0;       if (arow0 > Meff-1) arow0 = Meff-1;
  int arow1 = mBase + 64 + r0;  if (arow1 > Meff-1) arow1 = Meff-1;
  if (mode == 0 && lqp){ arow0 = qrows[arow0]; arow1 = qrows[arow1]; }
  const int wrowBase = (mode == 0 && !lqp) ? (768 + nBase) : nBase;
  const u16* ag0 = A + (size_t)arow0 * 768 + kc;
  const u16* ag1 = A + (size_t)arow1 * 768 + kc;
  const u16* bg0 = W + (size_t)(wrowBase + r0) * 768 + kc;
  const u16* bg1 = W + (size_t)(wrowBase + 64 + r0) * 768 + kc;
  const int toff0 = tid * 8, toff1 = (256 + tid) * 8;

  f32x4 acc[4][4] = {};
  const int wm = (w >> 1) * 64, wn = (w & 1) * 64;
  const int lm = l & 15;
  // swizzled read chunk: global chunk l>>4 of row with (row>>1)&3 == (l>>1)&3
  const int lkx = (((l >> 4) ^ ((l >> 1) & 3)) * 8);

#define STAGE(Ab, Bb, koff) do { \
    async16(ag0 + (koff), &Ab[toff0]); \
    async16(ag1 + (koff), &Ab[toff1]); \
    async16(bg0 + (koff), &Bb[toff0]); \
    async16(bg1 + (koff), &Bb[toff1]); } while(0)

#define COMPUTE(Ab, Bb) { \
    bf16x8 af[4], bfr[4]; \
    _Pragma("unroll") \
    for (int i = 0; i < 4; ++i) af[i]  = *(const bf16x8*)&Ab[(wm + i*16 + lm)*32 + lkx]; \
    _Pragma("unroll") \
    for (int j = 0; j < 4; ++j) bfr[j] = *(const bf16x8*)&Bb[(wn + j*16 + lm)*32 + lkx]; \
    __builtin_amdgcn_s_setprio(1); \
    _Pragma("unroll") \
    for (int i = 0; i < 4; ++i) \
      _Pragma("unroll") \
      for (int j = 0; j < 4; ++j) \
        acc[i][j] = __builtin_amdgcn_mfma_f32_16x16x32_bf16(af[i], bfr[j], acc[i][j], 0, 0, 0); \
    __builtin_amdgcn_s_setprio(0); }

#define VMW4 asm volatile("s_waitcnt vmcnt(4)" ::: "memory")
#define VMW0 asm volatile("s_waitcnt vmcnt(0)" ::: "memory")
#define BAR  __builtin_amdgcn_s_barrier()

  // prologue: tiles 0,1 in flight (8 outstanding)
  STAGE(As0, Bs0, 0);
  STAGE(As1, Bs1, 32);
  // steady state (2-deep): VMW4 drains tile t (keeps t+1 in flight); after the
  // post-compute barrier, t's buffer is restaged with t+2 -> one full phase of
  // flight time for every tile.
#pragma unroll
  for (int u = 0; u < 11; ++u){
    VMW4; BAR; COMPUTE(As0, Bs0); BAR; STAGE(As0, Bs0, u*64 + 64);
    VMW4; BAR; COMPUTE(As1, Bs1); BAR; STAGE(As1, Bs1, u*64 + 96);
  }
  VMW4; BAR; COMPUTE(As0, Bs0);   // t=22
  VMW0; BAR; COMPUTE(As1, Bs1);   // t=23 (drain)

#undef STAGE
#undef COMPUTE
#undef VMW4
#undef VMW0
#undef BAR

  // epilogue: C layout col=lane&15, row=(lane>>4)*4+reg
  if (mode == 1){
    // final: out[qrows[m]] = lout @ p_w^T + bias   (fp32)
#pragma unroll
    for (int i = 0; i < 4; ++i){
#pragma unroll
      for (int r = 0; r < 4; ++r){
        int m = mBase + wm + i*16 + ((l >> 4) << 2) + r;
        if (m < 3712){
          size_t base = (size_t)qrows[m] * 768;
#pragma unroll
          for (int j = 0; j < 4; ++j){
            int n = nBase + wn + j*16 + lm;
            Cout[base + n] = acc[i][j][r] + bias[n];
          }
        }
      }
    }
    return;
  }
  if (lqp){
    // local_q bf16
#pragma unroll
    for (int i = 0; i < 4; ++i){
#pragma unroll
      for (int r = 0; r < 4; ++r){
        int m = mBase + wm + i*16 + ((l >> 4) << 2) + r;
#pragma unroll
        for (int j = 0; j < 4; ++j){
          int n = nBase + wn + j*16 + lm;
          Clq[(size_t)m*768 + n] = f2b(acc[i][j][r]);
        }
      }
    }
  } else if (nBase < 768){
    // K bf16
#pragma unroll
    for (int i = 0; i < 4; ++i){
#pragma unroll
      for (int r = 0; r < 4; ++r){
        int m = mBase + wm + i*16 + ((l >> 4) << 2) + r;
        if (m < 36928){
#pragma unroll
          for (int j = 0; j < 4; ++j){
            int n = nBase + wn + j*16 + lm;
            Ck[(size_t)m*768 + n] = f2b(acc[i][j][r]);
          }
        }
      }
    }
  } else if (nBase < 1536){
    // Vt transposed per head: [(b*12+h)*64 + d][608]
#pragma unroll
    for (int i = 0; i < 4; ++i){
#pragma unroll
      for (int r = 0; r < 4; ++r){
        int m = mBase + wm + i*16 + ((l >> 4) << 2) + r;
        if (m < 36928){
          int bb = m / 577;
          int nn = m - bb*577;
#pragma unroll
          for (int j = 0; j < 4; ++j){
            int nf = nBase - 768 + wn + j*16 + lm;     // feature = h*64+d
            Cvt[((size_t)(bb*12 + (nf >> 6))*64 + (nf & 63))*608 + nn] = f2b(acc[i][j][r]);
          }
        }
      }
    }
  } else {
    // proj all rows fp32 + bias
#pragma unroll
    for (int i = 0; i < 4; ++i){
#pragma unroll
      for (int r = 0; r < 4; ++r){
        int m = mBase + wm + i*16 + ((l >> 4) << 2) + r;
        if (m < 36928){
          size_t base = (size_t)m * 768;
#pragma unroll
          for (int j = 0; j < 4; ++j){
            int nf = nBase - 1536 + wn + j*16 + lm;
            Cout[base + nf] = acc[i][j][r] + bias[nf];
          }
        }
      }
    }
  }
}

// ---------------- attention: 1D grid 3072, XCD-chunked (4 mt of one (h,b) share
// an XCD's L2). Register depth-1 prefetch on K (QK^T) and Vt (PV) hides global
// latency under MFMA. Softmax: 2 sweeps only (max, exp); normalization folded
// into the output epilogue via per-row inv (saves a full S RMW sweep + barrier).
#define SLD 580   // score LDS row stride in floats (577 data + 3 pad)
__global__ __launch_bounds__(256) void attn_kernel(
    const u16* __restrict__ lq, const u16* __restrict__ K,
    const u16* __restrict__ Vt, u16* __restrict__ lout)
{
  const int bid = blockIdx.x;
  const int wg = (bid & 7) * 384 + (bid >> 3);   // 3072 = 8*384 exact
  const int mt = wg & 3;
  const int hb = wg >> 2;
  const int h = hb % 12, b = hb / 12;

  __shared__ __align__(16) u16 qs[16*64];        // reused as red/inv after scores
  __shared__ __align__(16) float S[16*SLD];
  float* red  = (float*)qs;                      // 16*17 floats = 1088B
  float* invp = red + 16*17;                     // 16 floats (<= 2048B total)
  const int tid = threadIdx.x, w = tid >> 6, l = tid & 63;
  const int lm = l & 15, lk = (l >> 4) * 8;

  for (int idx = tid; idx < 1024; idx += 256){
    int r = idx >> 6, c = idx & 63;
    int gm = mt*16 + r;
    qs[idx] = (gm < 58) ? lq[((size_t)b*58 + gm)*768 + h*64 + c] : (u16)0;
  }
  __syncthreads();
  bf16x8 aq0 = *(const bf16x8*)&qs[lm*64 + lk];
  bf16x8 aq1 = *(const bf16x8*)&qs[lm*64 + 32 + lk];

  // scores: S[m][n] = (Q·K^T)*0.125 for n<577, reg double-buffered K loads
  const u16* Kb = K + (size_t)b*577*768 + h*64;
  {
    int t = w;
    int n = t*16 + lm; if (n > 576) n = 576;
    const u16* kp = Kb + (size_t)n*768;
    bf16x8 kb0 = *(const bf16x8*)&kp[lk];
    bf16x8 kb1 = *(const bf16x8*)&kp[32 + lk];
    while (t < 37){
      const int tn = t + 4;
      bf16x8 nb0 = kb0, nb1 = kb1;
      if (tn < 37){
        int n2 = tn*16 + lm; if (n2 > 576) n2 = 576;
        const u16* kp2 = Kb + (size_t)n2*768;
        nb0 = *(const bf16x8*)&kp2[lk];
        nb1 = *(const bf16x8*)&kp2[32 + lk];
      }
      f32x4 c = {};
      c = __builtin_amdgcn_mfma_f32_16x16x32_bf16(aq0, kb0, c, 0, 0, 0);
      c = __builtin_amdgcn_mfma_f32_16x16x32_bf16(aq1, kb1, c, 0, 0, 0);
      const int n0 = t*16;
      if (n0 + lm < 577){
#pragma unroll
        for (int r = 0; r < 4; ++r)
          S[(((l >> 4) << 2) + r)*SLD + n0 + lm] = c[r] * 0.125f;
      }
      kb0 = nb0; kb1 = nb1; t = tn;
    }
  }
  __syncthreads();

  // softmax: max pass + exp/sum pass (no normalize pass; inv applied at end)
  const int row = tid >> 4, g = tid & 15;
  float mx = -1e30f;
  for (int n = g; n < 577; n += 16) mx = fmaxf(mx, S[row*SLD + n]);
  red[row*17 + g] = mx;
  __syncthreads();
  float m2 = red[row*17];
#pragma unroll
  for (int i = 1; i < 16; ++i) m2 = fmaxf(m2, red[row*17 + i]);
  float sum = 0.f;
  for (int n = g; n < 577; n += 16){
    float e = __expf(S[row*SLD + n] - m2);
    S[row*SLD + n] = e;
    sum += e;
  }
  __syncthreads();
  red[row*17 + g] = sum;
  __syncthreads();
  if (g == 0){
    float s2 = 0.f;
#pragma unroll
    for (int i = 0; i < 16; ++i) s2 += red[row*17 + i];
    invp[row] = 1.f / s2;
  }
  __syncthreads();

  // O = (P_unnorm · V) * inv via Vt[b][h][d][n]; wave w owns d-tile w.
  // Vt row streamed with depth-1 register prefetch.
  const u16* Vb = Vt + ((size_t)(b*12 + h) * 64) * 608;
  const u16* Vrow = Vb + (size_t)(w*16 + lm)*608;
  f32x4 oc = {};
  bf16x8 bv = *(const bf16x8*)&Vrow[lk];
  for (int ks = 0; ks < 18; ++ks){
    const int kb = ks*32 + lk;
    bf16x8 bvn = bv;
    if (ks < 17) bvn = *(const bf16x8*)&Vrow[kb + 32];
    f32x4 p0 = *(const f32x4*)&S[lm*SLD + kb];
    f32x4 p1 = *(const f32x4*)&S[lm*SLD + kb + 4];
    bf16x8 af;
#pragma unroll
    for (int j = 0; j < 4; ++j){ af[j] = (short)f2b(p0[j]); af[4+j] = (short)f2b(p1[j]); }
    oc = __builtin_amdgcn_mfma_f32_16x16x32_bf16(af, bv, oc, 0, 0, 0);
    bv = bvn;
  }
  // tail n=576 (unnormalized), then scale by per-row inv
  {
    float vt576 = b2f(Vrow[576]);
#pragma unroll
    for (int r = 0; r < 4; ++r){
      int sr = (((l >> 4) << 2) + r);
      oc[r] = (oc[r] + S[sr*SLD + 576] * vt576) * invp[sr];
    }
  }
#pragma unroll
  for (int r = 0; r < 4; ++r){
    int ml = mt*16 + ((l >> 4) << 2) + r;
    if (ml < 58)
      lout[((size_t)b*58 + ml)*768 + h*64 + w*16 + lm] = f2b(oc[r]);
  }
}

// ---------------- launch ----------------
extern "C" void kernel_launch(void* const* d_in, const int* in_sizes, int n_in,
                              void* d_out, int out_size, void* d_ws, size_t ws_size,
                              hipStream_t stream)
{
  const void* x    = d_in[0];
  const void* aacc = d_in[1];
  const void* q_w  = d_in[2];
  const void* k_w  = d_in[3];
  const void* v_w  = d_in[4];
  const void* p_w  = d_in[5];
  const void* p_b  = d_in[6];

  const int M  = 36928;   // 64*577
  const int Ms = 3712;    // 64*58
  const int XE = M * 768;       // 28,360,704
  const int WE = 768 * 768;     // 589,824

  u16* Kbuf = (u16*)d_ws;                              // 36928*768
  u16* Vt   = Kbuf + (size_t)M * 768;                  // 768*64*608 (b*12+h, d, n)
  u16* lq   = Vt + (size_t)768 * 64 * 608;             // 3712*768
  u16* lout = lq + (size_t)Ms * 768;                   // 3712*768
  u16* xb   = lout + (size_t)Ms * 768;                 // 36928*768 bf16 x
  u16* qwb  = xb + (size_t)XE;                         // 4 weights bf16 [q;k;v;p]
  u16* pwb  = qwb + (size_t)3 * WE;
  float* biasf = (float*)(qwb + (size_t)4 * WE);       // 768 fp32
  int* qrows = (int*)(biasf + 768);                    // 3712 ints
  int* flagp = qrows + 3712;

  probe_kernel<<<1, 64, 0, stream>>>((const u16*)q_w, flagp);
  cvt_kernel<<<XE/8/256, 256, 0, stream>>>(x, xb, XE, flagp);
  cvtw4_kernel<<<1152, 256, 0, stream>>>(q_w, k_w, v_w, p_w, qwb, flagp);
  cvtb_kernel<<<3, 256, 0, stream>>>(p_b, biasf, 768, flagp);
  topk_kernel<<<64, 576, 0, stream>>>(aacc, qrows, flagp);

  // fused: K | Vt | proj-out (18 n-tiles x 289 m-tiles) + gathered lq (6 x 29)
  gemm_bt<<<5376, 256, 0, stream>>>(xb, qwb, Kbuf, Vt, (float*)d_out, lq,
                                    qrows, biasf, 0);
  // attention -> local_out
  attn_kernel<<<3072, 256, 0, stream>>>(lq, Kbuf, Vt, lout);
  // overwrite selected rows: out[qrows] = local_out @ proj_w^T + b
  gemm_bt<<<dim3(6, 29), 256, 0, stream>>>(lout, pwb, nullptr, nullptr,
                                           (float*)d_out, nullptr, qrows, biasf, 1);
}